// Round 1
// baseline (1158.660 us; speedup 1.0000x reference)
//
#include <hip/hip_runtime.h>

// Quantum-LSTM forward: B=512 samples, T=256 steps, 6 wires, 2 layers.
// One block per sample (recurrence is per-sample independent).
// 4 waves/block: phase1 -> waves 0..3 run circuits f,i,C,o; phase2 -> waves 0,1 run h,y.
// One complex amplitude per lane (64 amps = 64 lanes), gates via shfl_xor.
//
// Key reductions:
//  - AngleEmbedding on |0..0> is a product state: per-lane product of 6 complex
//    factors; half-angle cos/sin of atan(x) computed via rsqrt identities.
//  - All CNOTs are GF(2)-linear lane permutations, folded into static shuffle
//    masks (SHUF) and parity bit-masks (BMSK) -- zero runtime cost.
//  - RZ*RY*RX fused into one SU(2) per (circuit,layer,wire), precomputed in LDS.
//  - Z expvals via 6-stage FWHT on |amp|^2 + one indexed shuffle.

namespace {

constexpr int BATCH  = 512;
constexpr int TSTEPS = 256;

__device__ __forceinline__ float sigf(float v) { return 1.0f / (1.0f + __expf(-v)); }
// tanh(x) = 1 - 2/(1+e^{2x}) ; saturates correctly at +-inf
__device__ __forceinline__ float tanh_fast(float v) { return 1.0f - 2.0f / (1.0f + __expf(v + v)); }

// FWHT source lanes (rows of M2), packed 6 bits each
#define PACK_IDX ((0x2AULL)|(0x15ULL<<6)|(0x01ULL<<12)|(0x35ULL<<18)|(0x3AULL<<24)|(0x3DULL<<30))

__device__ __forceinline__ float run_circuit6(
    const float (&X)[6], const float4* __restrict__ fg,
    unsigned bitsmask, const float (&sgn)[6], int lane)
{
  // partner-lane XOR masks for rotations after the CNOT nets (M_l^{-1} e_i)
  constexpr unsigned SHUF[2][6] = {
    {0x0F,0x1E,0x3C,0x3B,0x3F,0x3D},
    {0x16,0x26,0x05,0x28,0x14,0x0A}};

  // ---- embedding: product state RY(atan(x)) then RZ(atan(x^2)) on |0..0> ----
  float ar = 0.f, ai = 0.f;
#pragma unroll
  for (int i = 0; i < 6; ++i) {
    float x = X[i];
    float t = x * x;
    // c1 = cos(atan(x)/2), s1 = sin(atan(x)/2)  (stable half-angle forms)
    float cth1 = rsqrtf(1.f + t);        // cos(atan(x))
    float sth1 = x * cth1;               // sin(atan(x))
    float u1 = 1.f + cth1;
    float r1 = rsqrtf(u1 + u1);
    float c1 = u1 * r1, s1 = sth1 * r1;
    // same for atan(x^2)
    float t2 = t * t;
    float cth2 = rsqrtf(1.f + t2);
    float sth2 = t * cth2;
    float u2 = 1.f + cth2;
    float r2 = rsqrtf(u2 + u2);
    float c2 = u2 * r2, s2 = sth2 * r2;
    bool bit = (lane >> i) & 1;
    float fr = (bit ? s1 :  c1) * c2;
    float fi = (bit ? s1 : -c1) * s2;
    if (i == 0) { ar = fr; ai = fi; }
    else {
      float nr = ar * fr - ai * fi;
      ai = ar * fi + ai * fr;
      ar = nr;
    }
  }

  // ---- 2 layers x 6 fused SU(2) gates (CNOTs folded into masks) ----
#pragma unroll
  for (int l = 0; l < 2; ++l) {
#pragma unroll
    for (int i = 0; i < 6; ++i) {
      float4 ga = fg[(l*6+i)*2+0];   // G00, G01
      float4 gb = fg[(l*6+i)*2+1];   // G10, G11
      float pr = __shfl_xor(ar, (int)SHUF[l][i], 64);
      float pi = __shfl_xor(ai, (int)SHUF[l][i], 64);
      bool bit = (bitsmask >> (l*6+i)) & 1u;
      float gdr = bit ? gb.z : ga.x, gdi = bit ? gb.w : ga.y;  // diag coeff
      float gor = bit ? gb.x : ga.z, goi = bit ? gb.y : ga.w;  // off-diag coeff
      float nr = gdr*ar - gdi*ai + gor*pr - goi*pi;
      float ni = gdr*ai + gdi*ar + gor*pi + goi*pr;
      ar = nr; ai = ni;
    }
  }

  // ---- expvals: FWHT over p = |amp|^2, pick Walsh coeffs at rows of M2 ----
  float p = fmaf(ar, ar, ai * ai);
#pragma unroll
  for (int k = 0; k < 6; ++k) {
    float q = __shfl_xor(p, 1 << k, 64);
    p = fmaf(sgn[k], p, q);   // lane: (-1)^{lane_k} * p + partner
  }
  int sh  = (lane < 6) ? (6 * lane) : 0;
  int idx = (int)((PACK_IDX >> sh) & 63ULL);
  return __shfl(p, idx, 64);  // lanes 0..5 hold Z_0..Z_5
}

} // namespace

__global__ __launch_bounds__(256, 2)
void qlstm_kernel(const float* __restrict__ x, const float* __restrict__ phi,
                  const float* __restrict__ Wc, const float* __restrict__ bc,
                  float* __restrict__ out)
{
  __shared__ float4 fG[144];      // 6 circuits x 12 gates x {G00G01, G10G11}
  __shared__ float4 wc4[6][4];    // Wc rows padded to 16
  __shared__ float  bc_s[6];
  __shared__ float  gates_s[4][6];
  __shared__ float  h_s[6];

  const int tid  = threadIdx.x;
  const int wave = tid >> 6;
  const int lane = tid & 63;
  const int b    = blockIdx.x;

  // ---- one-time init: fused gate matrices G = RZ*RY*RX per (g,l,i) ----
  if (tid < 72) {
    int g = tid / 12, rem = tid % 12, l = rem / 6, i = rem % 6;
    const float* w = phi + g*36 + l*18 + i*3;
    float sa, ca, sb, cb, sc, cc;
    sincosf(0.5f * w[0], &sa, &ca);
    sincosf(0.5f * w[1], &sb, &cb);
    sincosf(0.5f * w[2], &sc, &cc);
    // M = RY*RX
    float m00r =  cb*ca, m00i =  sb*sa;
    float m01r = -sb*ca, m01i = -cb*sa;
    float m10r =  sb*ca, m10i = -cb*sa;
    float m11r =  cb*ca, m11i = -sb*sa;
    // row0 *= e^{-ic/2}, row1 *= e^{+ic/2}
    float4 A, Bv;
    A.x  = m00r*cc + m00i*sc;  A.y  = m00i*cc - m00r*sc;
    A.z  = m01r*cc + m01i*sc;  A.w  = m01i*cc - m01r*sc;
    Bv.x = m10r*cc - m10i*sc;  Bv.y = m10i*cc + m10r*sc;
    Bv.z = m11r*cc - m11i*sc;  Bv.w = m11i*cc + m11r*sc;
    fG[2*tid] = A; fG[2*tid+1] = Bv;
  }
  if (tid < 24) {
    int j = tid / 4, q = tid % 4, k0 = q * 4;
    float4 v;
    v.x = (k0+0 < 14) ? Wc[j*14 + k0+0] : 0.f;
    v.y = (k0+1 < 14) ? Wc[j*14 + k0+1] : 0.f;
    v.z = (k0+2 < 14) ? Wc[j*14 + k0+2] : 0.f;
    v.w = (k0+3 < 14) ? Wc[j*14 + k0+3] : 0.f;
    wc4[j][q] = v;
  }
  if (tid < 6) { bc_s[tid] = bc[tid]; h_s[tid] = 0.f; }
  __syncthreads();

  // per-lane constants: coefficient-select parity bits (rows of M1, M2)
  constexpr unsigned BMSK[2][6] = {
    {0x18,0x30,0x39,0x0C,0x26,0x33},
    {0x2A,0x15,0x01,0x35,0x3A,0x3D}};
  unsigned bitsmask = 0;
#pragma unroll
  for (int l = 0; l < 2; ++l)
#pragma unroll
    for (int i = 0; i < 6; ++i)
      bitsmask |= (unsigned)(__popc(lane & BMSK[l][i]) & 1) << (l*6+i);
  float sgn[6];
#pragma unroll
  for (int k = 0; k < 6; ++k) sgn[k] = ((lane >> k) & 1) ? -1.f : 1.f;

  float c_reg[6];
#pragma unroll
  for (int i = 0; i < 6; ++i) c_reg[i] = 0.f;

  const float4* fgP1 = &fG[wave * 24];

  for (int t = 0; t < TSTEPS; ++t) {
    // ---- X = 2*sigmoid([x_t, h] @ Wc^T + bc) - 1  (redundant per lane) ----
    const float* xp = x + ((size_t)b * TSTEPS + t) * 8;
    float4 xa = *(const float4*)xp;
    float4 xb = *(const float4*)(xp + 4);
    float hv[6];
#pragma unroll
    for (int i = 0; i < 6; ++i) hv[i] = h_s[i];
    float X[6];
#pragma unroll
    for (int j = 0; j < 6; ++j) {
      float4 w0 = wc4[j][0], w1 = wc4[j][1], w2 = wc4[j][2], w3 = wc4[j][3];
      float acc = bc_s[j];
      acc = fmaf(xa.x, w0.x, acc); acc = fmaf(xa.y, w0.y, acc);
      acc = fmaf(xa.z, w0.z, acc); acc = fmaf(xa.w, w0.w, acc);
      acc = fmaf(xb.x, w1.x, acc); acc = fmaf(xb.y, w1.y, acc);
      acc = fmaf(xb.z, w1.z, acc); acc = fmaf(xb.w, w1.w, acc);
      acc = fmaf(hv[0], w2.x, acc); acc = fmaf(hv[1], w2.y, acc);
      acc = fmaf(hv[2], w2.z, acc); acc = fmaf(hv[3], w2.w, acc);
      acc = fmaf(hv[4], w3.x, acc); acc = fmaf(hv[5], w3.y, acc);
      X[j] = 1.f - 2.f / (1.f + __expf(acc));   // == 2*sigmoid(acc)-1
    }

    // ---- phase 1: waves 0..3 = circuits f,i,C,o on X ----
    float Wv = run_circuit6(X, fgP1, bitsmask, sgn, lane);
    if (lane < 6) gates_s[wave][lane] = sigf(Wv);
    __syncthreads();

    // ---- phase 2: cell update + circuits h (wave0), y (wave1) ----
    if (wave < 2) {
      float resc[6];
#pragma unroll
      for (int i = 0; i < 6; ++i) {
        float fg_ = gates_s[0][i], ig = gates_s[1][i];
        float Cg  = gates_s[2][i], og = gates_s[3][i];
        float cn = fmaf(fg_, c_reg[i], ig * Cg);
        c_reg[i] = cn;                      // waves 0,1 keep identical copies
        resc[i] = og * tanh_fast(cn);
      }
      float Wv2 = run_circuit6(resc, &fG[(4 + wave) * 24], bitsmask, sgn, lane);
      if (wave == 0) {
        if (lane < 6) h_s[lane] = Wv2;
      } else {
        if (lane < 6) out[((size_t)b * TSTEPS + t) * 6 + lane] = Wv2;
      }
    }
    __syncthreads();
  }

  // ---- final c, h ----
  if (tid == 0) {
    size_t cbase = (size_t)BATCH * TSTEPS * 6;
#pragma unroll
    for (int i = 0; i < 6; ++i) out[cbase + (size_t)b*6 + i] = c_reg[i];
#pragma unroll
    for (int i = 0; i < 6; ++i) out[cbase + (size_t)BATCH*6 + (size_t)b*6 + i] = h_s[i];
  }
}

extern "C" void kernel_launch(void* const* d_in, const int* in_sizes, int n_in,
                              void* d_out, int out_size, void* d_ws, size_t ws_size,
                              hipStream_t stream) {
  const float* x   = (const float*)d_in[0];
  const float* phi = (const float*)d_in[1];
  const float* Wc  = (const float*)d_in[2];
  const float* bc  = (const float*)d_in[3];
  float* out = (float*)d_out;
  (void)in_sizes; (void)n_in; (void)out_size; (void)d_ws; (void)ws_size;
  hipLaunchKernelGGL(qlstm_kernel, dim3(BATCH), dim3(256), 0, stream,
                     x, phi, Wc, bc, out);
}

// Round 2
// 559.769 us; speedup vs baseline: 2.0699x; 2.0699x over previous
//
#include <hip/hip_runtime.h>

// Quantum-LSTM forward. Structure as round 0 (512 blocks x 4 waves, verified
// constants) with three chain-shortening changes:
//  1. Gate pairs merged: 12 SU(2) gates -> 6 four-term stages with per-lane
//     PRECOMPUTED complex coeffs K0..K3 in VGPRs (valid since par(m2&B1)==0
//     for every pair). No LDS reads in the t-loop gate chain.
//  2. FWHT merged 2 stages at a time: 6 -> 3 shuffle-dependent steps.
//  3. X/trig computed lane-parallel (lane j owns wire j), broadcast via
//     v_readlane; removes the 64x-redundant dot product + trig.
// Shuffles are explicit: ds_swizzle for masks<32, ds_bpermute with
// inline-const xor address otherwise.

namespace {

constexpr int BATCH  = 512;
constexpr int TSTEPS = 256;

__device__ __forceinline__ float sigf(float v) { return 1.0f / (1.0f + __expf(-v)); }
__device__ __forceinline__ float tanh_fast(float v) { return 1.0f - 2.0f / (1.0f + __expf(v + v)); }

__device__ __forceinline__ float rl(float v, int l) {
  return __int_as_float(__builtin_amdgcn_readlane(__float_as_int(v), l));
}

template<int M>
__device__ __forceinline__ float shx(float v, int lane4) {
  if constexpr (M < 32) {
    return __int_as_float(__builtin_amdgcn_ds_swizzle(__float_as_int(v), 0x1F | (M << 10)));
  } else {
    return __int_as_float(__builtin_amdgcn_ds_bpermute(lane4 ^ (M << 2), __float_as_int(v)));
  }
}

// u(x) = K0 v(x) + K1 v(x^M1) + K2 v(x^M2) + K3 v(x^M1^M2)   (complex)
template<int M1, int M2, int M12>
__device__ __forceinline__ void stage(float& ar, float& ai, float4 kA, float4 kB, int lane4) {
  float v1r = shx<M1>(ar, lane4),  v1i = shx<M1>(ai, lane4);
  float v2r = shx<M2>(ar, lane4),  v2i = shx<M2>(ai, lane4);
  float v3r = shx<M12>(ar, lane4), v3i = shx<M12>(ai, lane4);
  float nr = kA.x * ar;
  nr = fmaf(-kA.y, ai,  nr); nr = fmaf(kA.z, v1r, nr); nr = fmaf(-kA.w, v1i, nr);
  nr = fmaf( kB.x, v2r, nr); nr = fmaf(-kB.y, v2i, nr);
  nr = fmaf( kB.z, v3r, nr); nr = fmaf(-kB.w, v3i, nr);
  float ni = kA.x * ai;
  ni = fmaf(kA.y, ar,  ni); ni = fmaf(kA.z, v1i, ni); ni = fmaf(kA.w, v1r, ni);
  ni = fmaf(kB.x, v2i, ni); ni = fmaf(kB.y, v2r, ni);
  ni = fmaf(kB.z, v3i, ni); ni = fmaf(kB.w, v3r, ni);
  ar = nr; ai = ni;
}

__device__ __forceinline__ void gate_chain(float& ar, float& ai,
    const float4 (&kA)[6], const float4 (&kB)[6], int lane4) {
  // pair-merged SHUF masks (m1, m2, m1^m2), layer0 then layer1
  stage<0x0F,0x1E,0x11>(ar, ai, kA[0], kB[0], lane4);
  stage<0x3C,0x3B,0x07>(ar, ai, kA[1], kB[1], lane4);
  stage<0x3F,0x3D,0x02>(ar, ai, kA[2], kB[2], lane4);
  stage<0x16,0x26,0x30>(ar, ai, kA[3], kB[3], lane4);
  stage<0x05,0x28,0x2D>(ar, ai, kA[4], kB[4], lane4);
  stage<0x14,0x0A,0x1E>(ar, ai, kA[5], kB[5], lane4);
}

// merged FWHT (pairs of bit-stages) + final gather
__device__ __forceinline__ float expvals(float ar, float ai, const float (&fs)[9],
                                         int lane4, int gaddr) {
  float p  = fmaf(ar, ar, ai * ai);
  float pa = shx<1>(p, lane4), pb = shx<2>(p, lane4), pc = shx<3>(p, lane4);
  p = fmaf(fs[0], p, fmaf(fs[1], pa, fmaf(fs[2], pb, pc)));
  pa = shx<4>(p, lane4); pb = shx<8>(p, lane4); pc = shx<12>(p, lane4);
  p = fmaf(fs[3], p, fmaf(fs[4], pa, fmaf(fs[5], pb, pc)));
  pa = shx<16>(p, lane4); pb = shx<32>(p, lane4); pc = shx<48>(p, lane4);
  p = fmaf(fs[6], p, fmaf(fs[7], pa, fmaf(fs[8], pb, pc)));
  return __int_as_float(__builtin_amdgcn_ds_bpermute(gaddr, __float_as_int(p)));
}

// half-angle products for wire value Xv: A=c1c2 B=c1s2 C=s1c2 D=s1s2
__device__ __forceinline__ void trig(float Xv, float& A_, float& B_, float& C_, float& D_) {
  float tq   = Xv * Xv;
  float cth1 = rsqrtf(1.f + tq);
  float sth1 = Xv * cth1;
  float u1   = 1.f + cth1, r1 = rsqrtf(u1 + u1);
  float c1   = u1 * r1,    s1 = sth1 * r1;
  float tq2  = tq * tq;
  float cth2 = rsqrtf(1.f + tq2);
  float sth2 = tq * cth2;
  float u2   = 1.f + cth2, r2 = rsqrtf(u2 + u2);
  float c2   = u2 * r2,    s2 = sth2 * r2;
  A_ = c1 * c2; B_ = c1 * s2; C_ = s1 * c2; D_ = s1 * s2;
}

// product-state embedding from broadcast wire factors
__device__ __forceinline__ void embed(float A_, float B_, float C_, float D_,
                                      int lane, float& ar, float& ai) {
  {
    float Aj = rl(A_,0), Bj = rl(B_,0), Cj = rl(C_,0), Dj = rl(D_,0);
    bool bj = lane & 1;
    ar = bj ? Cj : Aj;
    ai = bj ? Dj : -Bj;
  }
#pragma unroll
  for (int jj = 1; jj < 6; ++jj) {
    float Aj = rl(A_,jj), Bj = rl(B_,jj), Cj = rl(C_,jj), Dj = rl(D_,jj);
    bool bj = (lane >> jj) & 1;
    float fr = bj ? Cj : Aj;
    float fi = bj ? Dj : -Bj;
    float nr = ar * fr - ai * fi;
    ai = fmaf(ar, fi, ai * fr);
    ar = nr;
  }
}

// per-lane merged-pair coefficients for one circuit (reads fG in LDS)
__device__ __forceinline__ void make_K(const float4* fgc, int lane,
                                       float4 (&kA)[6], float4 (&kB)[6]) {
  constexpr unsigned BM[2][6] = {
    {0x18,0x30,0x39,0x0C,0x26,0x33},
    {0x2A,0x15,0x01,0x35,0x3A,0x3D}};
#pragma unroll
  for (int s = 0; s < 6; ++s) {
    int l = s / 3, i0 = (s % 3) * 2;
    float4 ga1 = fgc[(l*6+i0)*2],     gb1 = fgc[(l*6+i0)*2+1];
    float4 ga2 = fgc[(l*6+i0+1)*2],   gb2 = fgc[(l*6+i0+1)*2+1];
    bool p1 = __popc(lane & (int)BM[l][i0])   & 1;
    bool p2 = __popc(lane & (int)BM[l][i0+1]) & 1;
    float arr = p1 ? gb1.z : ga1.x, ari = p1 ? gb1.w : ga1.y;  // a (diag of g1)
    float brr = p1 ? gb1.x : ga1.z, bri = p1 ? gb1.y : ga1.w;  // b (off  of g1)
    float crr = p2 ? gb2.z : ga2.x, cri = p2 ? gb2.w : ga2.y;  // c (diag of g2)
    float drr = p2 ? gb2.x : ga2.z, dri = p2 ? gb2.y : ga2.w;  // d (off  of g2)
    kA[s] = make_float4(crr*arr - cri*ari, crr*ari + cri*arr,   // K0 = c*a
                        crr*brr - cri*bri, crr*bri + cri*brr);  // K1 = c*b
    kB[s] = make_float4(drr*arr - dri*ari, drr*ari + dri*arr,   // K2 = d*a
                        drr*brr - dri*bri, drr*bri + dri*brr);  // K3 = d*b
  }
}

#define PACK_IDX ((0x2AULL)|(0x15ULL<<6)|(0x01ULL<<12)|(0x35ULL<<18)|(0x3AULL<<24)|(0x3DULL<<30))

} // namespace

__global__ __launch_bounds__(256, 2)
void qlstm_kernel(const float* __restrict__ x, const float* __restrict__ phi,
                  const float* __restrict__ Wc, const float* __restrict__ bc,
                  float* __restrict__ out)
{
  __shared__ float4 fG[144];      // 6 circuits x 12 gates x {G00G01, G10G11}
  __shared__ float4 gates4[6];    // per-wire (f,i,C,o), sigmoided
  __shared__ float  h_s[6];

  const int tid   = threadIdx.x;
  const int wave  = tid >> 6;
  const int lane  = tid & 63;
  const int lane4 = lane << 2;
  const int b     = blockIdx.x;

  // ---- one-time: fused gate matrices G = RZ*RY*RX per (circuit,layer,wire) ----
  if (tid < 72) {
    int g = tid / 12, rem = tid % 12, l = rem / 6, i = rem % 6;
    const float* w = phi + g*36 + l*18 + i*3;
    float sa, ca, sb, cb, sc, cc;
    sincosf(0.5f * w[0], &sa, &ca);
    sincosf(0.5f * w[1], &sb, &cb);
    sincosf(0.5f * w[2], &sc, &cc);
    float m00r =  cb*ca, m00i =  sb*sa;
    float m01r = -sb*ca, m01i = -cb*sa;
    float m10r =  sb*ca, m10i = -cb*sa;
    float m11r =  cb*ca, m11i = -sb*sa;
    float4 A, Bv;
    A.x  = m00r*cc + m00i*sc;  A.y  = m00i*cc - m00r*sc;
    A.z  = m01r*cc + m01i*sc;  A.w  = m01i*cc - m01r*sc;
    Bv.x = m10r*cc - m10i*sc;  Bv.y = m10i*cc + m10r*sc;
    Bv.z = m11r*cc - m11i*sc;  Bv.w = m11i*cc + m11r*sc;
    fG[2*tid] = A; fG[2*tid+1] = Bv;
  }
  if (tid < 6) h_s[tid] = 0.f;
  __syncthreads();

  // ---- per-wave/lane loop-invariants ----
  const int j = (lane < 6) ? lane : 0;           // owned wire
  float Wr[14];
#pragma unroll
  for (int k = 0; k < 14; ++k) Wr[k] = Wc[j*14 + k];
  const float bcj = bc[j];

  float sg0 = (lane & 1)  ? -1.f : 1.f;
  float sg1 = (lane & 2)  ? -1.f : 1.f;
  float sg2 = (lane & 4)  ? -1.f : 1.f;
  float sg3 = (lane & 8)  ? -1.f : 1.f;
  float sg4 = (lane & 16) ? -1.f : 1.f;
  float sg5 = (lane & 32) ? -1.f : 1.f;
  float fs[9] = { sg0*sg1, sg1, sg0,  sg2*sg3, sg3, sg2,  sg4*sg5, sg5, sg4 };

  int sh    = (lane < 6) ? (6 * lane) : 0;
  int gaddr = (int)((PACK_IDX >> sh) & 63ULL) << 2;

  float4 kA1[6], kB1[6], kA2[6], kB2[6];
  make_K(&fG[wave * 24], lane, kA1, kB1);                 // phase-1 circuit
  make_K(&fG[(4 + (wave & 1)) * 24], lane, kA2, kB2);     // phase-2 circuit (waves 0,1)

  float c_sc  = 0.f;   // lane i (<6) of waves 0,1 owns c_i
  float hlast = 0.f;

  const float* xbase = x + (size_t)b * TSTEPS * 8;
  float4 xa = *(const float4*)(xbase);
  float4 xb = *(const float4*)(xbase + 4);

  for (int t = 0; t < TSTEPS; ++t) {
    // ---- phase 1: X_j in lane j, broadcast trig, circuit (f,i,C,o per wave) ----
    float hv0 = h_s[0], hv1 = h_s[1], hv2 = h_s[2];
    float hv3 = h_s[3], hv4 = h_s[4], hv5 = h_s[5];
    float acc = bcj;
    acc = fmaf(xa.x, Wr[0],  acc); acc = fmaf(xa.y, Wr[1],  acc);
    acc = fmaf(xa.z, Wr[2],  acc); acc = fmaf(xa.w, Wr[3],  acc);
    acc = fmaf(xb.x, Wr[4],  acc); acc = fmaf(xb.y, Wr[5],  acc);
    acc = fmaf(xb.z, Wr[6],  acc); acc = fmaf(xb.w, Wr[7],  acc);
    acc = fmaf(hv0,  Wr[8],  acc); acc = fmaf(hv1,  Wr[9],  acc);
    acc = fmaf(hv2,  Wr[10], acc); acc = fmaf(hv3,  Wr[11], acc);
    acc = fmaf(hv4,  Wr[12], acc); acc = fmaf(hv5,  Wr[13], acc);
    float Xj = 1.f - 2.f / (1.f + __expf(acc));

    // prefetch next x (overlaps the circuit)
    int tn = (t + 1 < TSTEPS) ? (t + 1) : t;
    float4 xa_n = *(const float4*)(xbase + (size_t)tn * 8);
    float4 xb_n = *(const float4*)(xbase + (size_t)tn * 8 + 4);

    float A_, B_, C_, D_;
    trig(Xj, A_, B_, C_, D_);
    float ar, ai;
    embed(A_, B_, C_, D_, lane, ar, ai);
    gate_chain(ar, ai, kA1, kB1, lane4);
    float Wv  = expvals(ar, ai, fs, lane4, gaddr);
    float sgv = sigf(Wv);
    if (lane < 6) ((float*)&gates4[lane])[wave] = sgv;
    __syncthreads();

    // ---- phase 2: cell update + circuits h (wave0), y (wave1) ----
    if (wave < 2) {
      float4 g4 = gates4[j];                       // (f,i,C,o) for wire j
      float cn  = fmaf(g4.x, c_sc, g4.y * g4.z);
      c_sc = cn;
      float resc = g4.w * tanh_fast(cn);
      float A2, B2, C2, D2;
      trig(resc, A2, B2, C2, D2);
      float ar2, ai2;
      embed(A2, B2, C2, D2, lane, ar2, ai2);
      gate_chain(ar2, ai2, kA2, kB2, lane4);
      float Wv2 = expvals(ar2, ai2, fs, lane4, gaddr);
      if (wave == 0) {
        if (lane < 6) h_s[lane] = Wv2;
        hlast = Wv2;
      } else if (lane < 6) {
        out[((size_t)b * TSTEPS + t) * 6 + lane] = Wv2;
      }
    }
    xa = xa_n; xb = xb_n;
    __syncthreads();
  }

  // ---- final c, h ----
  if (wave == 0 && lane < 6) {
    size_t cbase = (size_t)BATCH * TSTEPS * 6;
    out[cbase + (size_t)b * 6 + lane] = c_sc;
    out[cbase + (size_t)BATCH * 6 + (size_t)b * 6 + lane] = hlast;
  }
}

extern "C" void kernel_launch(void* const* d_in, const int* in_sizes, int n_in,
                              void* d_out, int out_size, void* d_ws, size_t ws_size,
                              hipStream_t stream) {
  const float* x   = (const float*)d_in[0];
  const float* phi = (const float*)d_in[1];
  const float* Wc  = (const float*)d_in[2];
  const float* bc  = (const float*)d_in[3];
  float* out = (float*)d_out;
  (void)in_sizes; (void)n_in; (void)out_size; (void)d_ws; (void)ws_size;
  hipLaunchKernelGGL(qlstm_kernel, dim3(BATCH), dim3(256), 0, stream,
                     x, phi, Wc, bc, out);
}